// Round 11
// baseline (74.702 us; speedup 1.0000x reference)
//
#include <hip/hip_runtime.h>

#define TSD 512      // TS (feature dim)
#define SRC 256
#define TGT 256
#define NB  4        // batch
#define KSCALE 2.885390081777927f       // 2*log2(e): exp2(K*x) == exp(2x)
#define SCALE  9.5367431640625e-07f     // 2^-20: overflow headroom for 4-way product
#define EPSV   1e-20f

typedef __attribute__((ext_vector_type(8))) short short8;
typedef __attribute__((ext_vector_type(4))) float f32x4;

// ---------------------------------------------------------------------------
// Split fp32 -> bf16 (hi, lo) with RNE. A = [hid; enc] (2048x512),
// W kept row-major (512x1024).
// ---------------------------------------------------------------------------
__device__ __forceinline__ ushort bf16_hi(float x, float& back) {
    unsigned u = __float_as_uint(x);
    unsigned r = (u + 0x7FFFu + ((u >> 16) & 1u)) >> 16;
    back = __uint_as_float(r << 16);
    return (ushort)r;
}

__global__ __launch_bounds__(256) void conv_kernel(
    const float* __restrict__ hid, const float* __restrict__ enc,
    const float* __restrict__ W,
    ushort* __restrict__ Ah, ushort* __restrict__ Al,
    ushort* __restrict__ Wh, ushort* __restrict__ Wl)
{
    const int i4 = blockIdx.x * 256 + threadIdx.x;   // float4 index
    const int NA4 = (2048 * 512) / 4;                // 262144
    const int NW4 = (512 * 1024) / 4;                // 131072

    float4 x;
    ushort* dh;
    ushort* dl;
    int off;
    if (i4 < NA4) {
        x = (i4 < NA4 / 2) ? reinterpret_cast<const float4*>(hid)[i4]
                           : reinterpret_cast<const float4*>(enc)[i4 - NA4 / 2];
        dh = Ah; dl = Al; off = i4;
    } else if (i4 < NA4 + NW4) {
        x = reinterpret_cast<const float4*>(W)[i4 - NA4];
        dh = Wh; dl = Wl; off = i4 - NA4;
    } else {
        return;
    }

    float bx, by, bz, bw, d;
    ushort4 hi, lo;
    hi.x = bf16_hi(x.x, bx); lo.x = bf16_hi(x.x - bx, d);
    hi.y = bf16_hi(x.y, by); lo.y = bf16_hi(x.y - by, d);
    hi.z = bf16_hi(x.z, bz); lo.z = bf16_hi(x.z - bz, d);
    hi.w = bf16_hi(x.w, bw); lo.w = bf16_hi(x.w - bw, d);
    reinterpret_cast<ushort4*>(dh)[off] = hi;
    reinterpret_cast<ushort4*>(dl)[off] = lo;
}

// ---------------------------------------------------------------------------
// Split-bf16 MFMA projection: C = X.W^T via Ah.Wh + Ah.Wl + Al.Wh.
// Grid (N/64=8, M/64=16, z), block 256 = 4 waves; wave (wm,wn) owns 32x32.
// z=0: hpE2[r][o]   = S*exp2(K*C)/v[o]          (row-major)
// z=1: epE[b][o][s] = exp2(K*(C + bias[o]))     (transposed via LDS tile)
// C/D frag layout (verified m89): row=(lane>>4)*4+reg, col=lane&15.
// A/B frags: 8 contiguous bf16 along K at row (lane&15), k-octet (lane>>4).
// ---------------------------------------------------------------------------
__global__ __launch_bounds__(256) void mfma_proj_kernel(
    const ushort* __restrict__ Ah, const ushort* __restrict__ Al,
    const ushort* __restrict__ Wh, const ushort* __restrict__ Wl,
    const float* __restrict__ bias, const float* __restrict__ v,
    float* __restrict__ hpE2, float* __restrict__ epE)
{
    __shared__ float tile[64][68];

    const int z  = blockIdx.z;
    const int o0 = blockIdx.x * 64;
    const int r0 = blockIdx.y * 64;           // row within this source
    const int arow0 = z * (NB * TGT) + r0;    // row in A arrays (2048)
    const int wofs  = z * TSD;

    const int tid  = threadIdx.x;
    const int lane = tid & 63;
    const int w    = tid >> 6;
    const int wm   = w >> 1, wn = w & 1;

    const int mrow = lane & 15;
    const int koct = (lane >> 4) * 8;

    f32x4 acc00 = {0.f, 0.f, 0.f, 0.f};
    f32x4 acc01 = {0.f, 0.f, 0.f, 0.f};
    f32x4 acc10 = {0.f, 0.f, 0.f, 0.f};
    f32x4 acc11 = {0.f, 0.f, 0.f, 0.f};

    const size_t aBase0 = (size_t)(arow0 + wm * 32 + mrow) * TSD + koct;
    const size_t aBase1 = (size_t)(arow0 + wm * 32 + 16 + mrow) * TSD + koct;
    const size_t bBase0 = (size_t)(o0 + wn * 32 + mrow) * (2 * TSD) + wofs + koct;
    const size_t bBase1 = (size_t)(o0 + wn * 32 + 16 + mrow) * (2 * TSD) + wofs + koct;

    #pragma unroll
    for (int p = 0; p < 3; ++p) {
        const ushort* __restrict__ Ap = (p < 2) ? Ah : Al;
        const ushort* __restrict__ Bp = (p == 1) ? Wl : Wh;
        #pragma unroll 4
        for (int k0 = 0; k0 < TSD; k0 += 32) {
            short8 a0 = *reinterpret_cast<const short8*>(&Ap[aBase0 + k0]);
            short8 a1 = *reinterpret_cast<const short8*>(&Ap[aBase1 + k0]);
            short8 b0 = *reinterpret_cast<const short8*>(&Bp[bBase0 + k0]);
            short8 b1 = *reinterpret_cast<const short8*>(&Bp[bBase1 + k0]);
            acc00 = __builtin_amdgcn_mfma_f32_16x16x32_bf16(a0, b0, acc00, 0, 0, 0);
            acc01 = __builtin_amdgcn_mfma_f32_16x16x32_bf16(a0, b1, acc01, 0, 0, 0);
            acc10 = __builtin_amdgcn_mfma_f32_16x16x32_bf16(a1, b0, acc10, 0, 0, 0);
            acc11 = __builtin_amdgcn_mfma_f32_16x16x32_bf16(a1, b1, acc11, 0, 0, 0);
        }
    }

    // scatter accumulators into LDS tile [row][col]
    const int crow = (lane >> 4) * 4;
    const int ccol = lane & 15;
    #pragma unroll
    for (int reg = 0; reg < 4; ++reg) {
        tile[wm * 32 + crow + reg][wn * 32 + ccol]           = acc00[reg];
        tile[wm * 32 + crow + reg][wn * 32 + 16 + ccol]      = acc01[reg];
        tile[wm * 32 + 16 + crow + reg][wn * 32 + ccol]      = acc10[reg];
        tile[wm * 32 + 16 + crow + reg][wn * 32 + 16 + ccol] = acc11[reg];
    }
    __syncthreads();

    if (z) {
        // epE[b][o][s] = exp2(K*(C+bias[o])), transposed coalesced store
        const int bb_ = r0 >> 8;
        const int s0  = (r0 & 255) + (tid & 15) * 4;
        #pragma unroll
        for (int it = 0; it < 4; ++it) {
            const int ol = it * 16 + (tid >> 4);
            const float bj = bias[o0 + ol];
            float4 val;
            val.x = __builtin_amdgcn_exp2f((tile[(tid & 15) * 4 + 0][ol] + bj) * KSCALE);
            val.y = __builtin_amdgcn_exp2f((tile[(tid & 15) * 4 + 1][ol] + bj) * KSCALE);
            val.z = __builtin_amdgcn_exp2f((tile[(tid & 15) * 4 + 2][ol] + bj) * KSCALE);
            val.w = __builtin_amdgcn_exp2f((tile[(tid & 15) * 4 + 3][ol] + bj) * KSCALE);
            *reinterpret_cast<float4*>(&epE[((size_t)bb_ * TSD + o0 + ol) * SRC + s0]) = val;
        }
    } else {
        // hpE2[r][o] = S*exp2(K*C)/v[o], row-major coalesced store
        const int r_l = tid >> 2;
        const int c0  = (tid & 3) * 16;
        #pragma unroll
        for (int j = 0; j < 4; ++j) {
            const int oc = c0 + j * 4;
            float4 q;
            q.x = __builtin_amdgcn_exp2f(tile[r_l][oc + 0] * KSCALE) *
                  (SCALE * __builtin_amdgcn_rcpf(fmaxf(v[o0 + oc + 0], EPSV)));
            q.y = __builtin_amdgcn_exp2f(tile[r_l][oc + 1] * KSCALE) *
                  (SCALE * __builtin_amdgcn_rcpf(fmaxf(v[o0 + oc + 1], EPSV)));
            q.z = __builtin_amdgcn_exp2f(tile[r_l][oc + 2] * KSCALE) *
                  (SCALE * __builtin_amdgcn_rcpf(fmaxf(v[o0 + oc + 2], EPSV)));
            q.w = __builtin_amdgcn_exp2f(tile[r_l][oc + 3] * KSCALE) *
                  (SCALE * __builtin_amdgcn_rcpf(fmaxf(v[o0 + oc + 3], EPSV)));
            *reinterpret_cast<float4*>(&hpE2[(size_t)(r0 + r_l) * TSD + o0 + oc]) = q;
        }
    }
}

__device__ __forceinline__ float wave_red_sum(float v) {
    #pragma unroll
    for (int off = 1; off < 64; off <<= 1) v += __shfl_xor(v, off, 64);
    return v;
}
__device__ __forceinline__ float wave_red_max(float v) {
    #pragma unroll
    for (int off = 1; off < 64; off <<= 1) v = fmaxf(v, __shfl_xor(v, off, 64));
    return v;
}

// ---------------------------------------------------------------------------
// Phase A: P[t][s] = sum_o v[o]/(z+1); w' = Eh2s*Ee + ivs (one fma),
// 4 t-rows share one rcp. Grid (TGT/4, NB, 2 s-halves), 512 thr = 8 waves.
// ---------------------------------------------------------------------------
__global__ __launch_bounds__(512) void score_kernel(
    const float* __restrict__ hpE2, const float* __restrict__ epE,
    const float* __restrict__ v, float* __restrict__ P_out)
{
    __shared__ float4 eh4[TSD];         // Eh2s for 4 t rows   (8 KB)
    __shared__ float ivs[TSD];          // S/v[o]              (2 KB)
    __shared__ float accs[4][8][128];   // [t][wave][s_local]  (16 KB)

    const int tid = threadIdx.x;
    const int b  = blockIdx.y;
    const int t0 = blockIdx.x * 4;
    const int sh = blockIdx.z;          // s-half

    {
        const int row = tid >> 7;            // 0..3
        const int oq  = (tid & 127) * 4;
        const float4 hh = *reinterpret_cast<const float4*>(
            &hpE2[((size_t)(b * TGT + t0 + row)) * TSD + oq]);
        ((float*)&eh4[oq + 0])[row] = hh.x;
        ((float*)&eh4[oq + 1])[row] = hh.y;
        ((float*)&eh4[oq + 2])[row] = hh.z;
        ((float*)&eh4[oq + 3])[row] = hh.w;
        ivs[tid] = SCALE * __builtin_amdgcn_rcpf(fmaxf(v[tid], EPSV));
    }
    __syncthreads();

    const int w    = __builtin_amdgcn_readfirstlane(tid >> 6);  // wave 0..7
    const int lane = tid & 63;
    const float* __restrict__ epb =
        epE + (size_t)b * TSD * SRC + (size_t)(w * 64) * SRC + sh * 128 + 2 * lane;

    float acc[4][2] = {};   // [t][s-sub]
    #pragma unroll 4
    for (int oi = 0; oi < 64; ++oi) {
        const int o = w * 64 + oi;
        const float2 ee = *reinterpret_cast<const float2*>(epb + (size_t)oi * SRC);
        const float4 eh = eh4[o];       // uniform -> ds_read_b128 broadcast
        const float  iv = ivs[o];       // uniform -> ds_read_b32 broadcast
        const float eer[2] = {ee.x, ee.y};
        #pragma unroll
        for (int k = 0; k < 2; ++k) {
            const float e = eer[k];
            const float w0 = fmaf(eh.x, e, iv);
            const float w1 = fmaf(eh.y, e, iv);
            const float w2 = fmaf(eh.z, e, iv);
            const float w3 = fmaf(eh.w, e, iv);
            const float p01 = w0 * w1;
            const float p23 = w2 * w3;
            const float r   = __builtin_amdgcn_rcpf(p01 * p23);
            const float rp01 = r * p01;       // = 1/p23
            const float rp23 = r * p23;       // = 1/p01
            acc[0][k] = fmaf(rp23, w1, acc[0][k]);
            acc[1][k] = fmaf(rp23, w0, acc[1][k]);
            acc[2][k] = fmaf(rp01, w3, acc[2][k]);
            acc[3][k] = fmaf(rp01, w2, acc[3][k]);
        }
    }
    #pragma unroll
    for (int t = 0; t < 4; ++t) {
        float2 r2; r2.x = acc[t][0]; r2.y = acc[t][1];
        *reinterpret_cast<float2*>(&accs[t][w][2 * lane]) = r2;
    }
    __syncthreads();

    {
        const int t = tid >> 7;
        const int s = tid & 127;
        float Psum = 0.f;
        #pragma unroll
        for (int k = 0; k < 8; ++k) Psum += accs[t][k][s];
        P_out[((size_t)(b * TGT + t0 + t)) * SRC + sh * 128 + s] = Psum * SCALE;
    }
}

// ---------------------------------------------------------------------------
// Phase B: softmax. One wave per target row (4 rows/block). In-place on probs.
// ---------------------------------------------------------------------------
__global__ __launch_bounds__(256) void softmax_kernel(
    const int* __restrict__ mask, const float* __restrict__ v,
    float* __restrict__ probs)
{
    const int tid  = threadIdx.x;
    const int lane = tid & 63;
    const int rowg = blockIdx.x * 4 + (tid >> 6);   // global row: b*TGT + t
    const int b    = rowg >> 8;

    float sv = 0.f;
    #pragma unroll
    for (int k = 0; k < 8; ++k) sv += v[lane + 64 * k];
    const float sumv = wave_red_sum(sv);

    const size_t base = (size_t)rowg * SRC + 4 * lane;
    const float4 Pv = *reinterpret_cast<const float4*>(&probs[base]);
    float sc[4];
    sc[0] = sumv - 2.f * Pv.x;
    sc[1] = sumv - 2.f * Pv.y;
    sc[2] = sumv - 2.f * Pv.z;
    sc[3] = sumv - 2.f * Pv.w;

    const float lmax = fmaxf(fmaxf(sc[0], sc[1]), fmaxf(sc[2], sc[3]));
    const float m = wave_red_max(lmax);
    float e[4];
    #pragma unroll
    for (int i = 0; i < 4; ++i) e[i] = __expf(sc[i] - m);
    const float sE = wave_red_sum(e[0] + e[1] + e[2] + e[3]);

    const int4 mk = *reinterpret_cast<const int4*>(&mask[b * SRC + 4 * lane]);
    float mq[4];
    mq[0] = (e[0] / sE) * (float)mk.x;
    mq[1] = (e[1] / sE) * (float)mk.y;
    mq[2] = (e[2] / sE) * (float)mk.z;
    mq[3] = (e[3] / sE) * (float)mk.w;
    const float sM = wave_red_sum(mq[0] + mq[1] + mq[2] + mq[3]);
    const float inv = 1.f / (sM + 1e-12f);
    float4 pv;
    pv.x = mq[0] * inv; pv.y = mq[1] * inv; pv.z = mq[2] * inv; pv.w = mq[3] * inv;
    *reinterpret_cast<float4*>(&probs[base]) = pv;
}

// ---------------------------------------------------------------------------
// Phase C: context. Grid (TGT/4, NB, 2 d-halves), 256 thr.
// ---------------------------------------------------------------------------
__global__ __launch_bounds__(256) void ctx_kernel(
    const float* __restrict__ probs, const float* __restrict__ enc,
    float* __restrict__ ctx_out)
{
    __shared__ float p_lds[4][SRC];

    const int tid = threadIdx.x;
    const int b   = blockIdx.y;
    const int t0  = blockIdx.x * 4;
    const int dh  = blockIdx.z;

    #pragma unroll
    for (int t = 0; t < 4; ++t)
        p_lds[t][tid] = probs[((size_t)(b * TGT + t0 + t)) * SRC + tid];
    __syncthreads();

    const float* __restrict__ encb = enc + (size_t)b * SRC * TSD + dh * 256 + tid;
    float c0 = 0.f, c1 = 0.f, c2 = 0.f, c3 = 0.f;
    #pragma unroll 4
    for (int s2 = 0; s2 < SRC; ++s2) {
        const float ev = encb[(size_t)s2 * TSD];
        c0 = fmaf(p_lds[0][s2], ev, c0);
        c1 = fmaf(p_lds[1][s2], ev, c1);
        c2 = fmaf(p_lds[2][s2], ev, c2);
        c3 = fmaf(p_lds[3][s2], ev, c3);
    }
    const size_t obase = ((size_t)(b * TGT + t0)) * TSD + dh * 256 + tid;
    ctx_out[obase]           = c0;
    ctx_out[obase + TSD]     = c1;
    ctx_out[obase + 2 * TSD] = c2;
    ctx_out[obase + 3 * TSD] = c3;
}

extern "C" void kernel_launch(void* const* d_in, const int* in_sizes, int n_in,
                              void* d_out, int out_size, void* d_ws, size_t ws_size,
                              hipStream_t stream) {
    const float* hid  = (const float*)d_in[0];   // (4,256,512)
    const float* enc  = (const float*)d_in[1];   // (4,256,512)
    const int*   mask = (const int*)  d_in[2];   // (4,256)
    const float* W    = (const float*)d_in[3];   // (512,1024)
    const float* bias = (const float*)d_in[4];   // (512,)
    const float* v    = (const float*)d_in[5];   // (512,)

    float* out   = (float*)d_out;
    float* ctx   = out;                       // 4*256*512
    float* probs = out + NB * TGT * TSD;      // 4*256*256 (holds P, then probs)

    float* hpE2 = (float*)d_ws;               // 1024*512 f32               2 MB
    float* epE  = hpE2 + NB * TGT * TSD;      // 4*512*256 f32              2 MB
    ushort* Ah  = (ushort*)(epE + NB * TSD * SRC);   // 2048*512 bf16       2 MB
    ushort* Al  = Ah + 2048 * 512;                   //                     2 MB
    ushort* Wh  = Al + 2048 * 512;                   // 512*1024 bf16       1 MB
    ushort* Wl  = Wh + 512 * 1024;                   //                     1 MB

    conv_kernel<<<dim3(1536), 256, 0, stream>>>(hid, enc, W, Ah, Al, Wh, Wl);

    dim3 mg(TSD / 64, (NB * TGT) / 64, 2);
    mfma_proj_kernel<<<mg, 256, 0, stream>>>(Ah, Al, Wh, Wl, bias, v, hpE2, epE);

    dim3 ag(TGT / 4, NB, 2);
    score_kernel<<<ag, 512, 0, stream>>>(hpE2, epE, v, probs);

    softmax_kernel<<<dim3(NB * TGT / 4), 256, 0, stream>>>(mask, v, probs);

    dim3 cg(TGT / 4, NB, 2);
    ctx_kernel<<<cg, 256, 0, stream>>>(probs, enc, ctx);
}